// Round 1
// baseline (2456.719 us; speedup 1.0000x reference)
//
#include <hip/hip_runtime.h>
#include <hip/hip_bf16.h>
#include <hip/hip_fp16.h>

#define B_ 64
#define T_ 256
#define D_ 256
#define H_ 512
#define C_ 1000
#define M_ (B_*T_)      // 16384
#define KFC (T_*H_)     // 131072

typedef _Float16 f16x2 __attribute__((ext_vector_type(2)));
typedef _Float16 f16x4 __attribute__((ext_vector_type(4)));
typedef _Float16 f16x8 __attribute__((ext_vector_type(8)));
typedef float    f32x4 __attribute__((ext_vector_type(4)));

#if defined(__has_builtin)
#if __has_builtin(__builtin_amdgcn_fdot2)
#define FDOT2(w,h,acc) (acc) = __builtin_amdgcn_fdot2((w),(h),(acc),false)
#endif
#endif
#ifndef FDOT2
#define FDOT2(w,h,acc) (acc) += (float)(w)[0]*(float)(h)[0] + (float)(w)[1]*(float)(h)[1]
#endif

__device__ __forceinline__ float tanh_fast(float x){
  float e = __expf(2.0f*x);
  return 1.0f - 2.0f/(e + 1.0f);
}

// ---------------- prep kernels ----------------

// inp f32 -> f16, 4 elems/thread
__global__ void k_cvt_x(const float* __restrict__ x, _Float16* __restrict__ o){
  int i = (blockIdx.x*256 + threadIdx.x)*4;
  float4 v = *(const float4*)(x + i);
  f16x4 r = {(_Float16)v.x,(_Float16)v.y,(_Float16)v.z,(_Float16)v.w};
  *(f16x4*)(o + i) = r;
}

// W [N=512][K] f32 row-major  ->  WB [K/32][512][4][8] f16 (MFMA B-frag layout)
__global__ void k_pack_wb(const float* __restrict__ W, _Float16* __restrict__ WB, int K){
  int id = blockIdx.x*256 + threadIdx.x;     // (K/32)*512*4 total
  int g  = id & 3;
  int n  = (id >> 2) & 511;
  int kt = id >> 11;
  const float* src = W + (size_t)n*K + kt*32 + g*8;
  _Float16* dst = WB + ((size_t)(kt*512 + n)*4 + g)*8;
  #pragma unroll
  for (int j=0;j<8;++j) dst[j] = (_Float16)src[j];
}

// W_hh [512][512] f32 -> W8 [64][512][8] f16 (k-chunk-8 interleave, coalesced stream)
__global__ void k_pack_w8(const float* __restrict__ W, _Float16* __restrict__ W8){
  int id = blockIdx.x*256 + threadIdx.x;     // 64*512
  int n  = id & 511;
  int kc = id >> 9;
  const float* src = W + (size_t)n*512 + kc*8;
  _Float16* dst = W8 + (size_t)(kc*512 + n)*8;
  #pragma unroll
  for (int j=0;j<8;++j) dst[j] = (_Float16)src[j];
}

__global__ void k_bias(const float* __restrict__ a, const float* __restrict__ b,
                       float* __restrict__ o){
  int i = blockIdx.x*256 + threadIdx.x;
  if (i < 512) o[i] = a[i] + b[i];
}

// ---------------- affine GEMM: XW[m][n] = sum_k X[m][k]*W[n][k] ----------------
// X: [M][K] f16 row-major (A), WB: packed B-frag layout. grid (M/64, 512/64), block 256.
template<int K>
__global__ __launch_bounds__(256,4) void k_affine(const _Float16* __restrict__ X,
        const _Float16* __restrict__ WB, float* __restrict__ XW){
  __shared__ __align__(16) char Asb[64*128];   // 64 rows x 64 k f16, xor-swizzled
  const int m0 = blockIdx.x*64, n0 = blockIdx.y*64;
  const int tid = threadIdx.x, lane = tid & 63, w = tid >> 6;
  f32x4 acc[4] = {{0,0,0,0},{0,0,0,0},{0,0,0,0},{0,0,0,0}};

  for (int kc = 0; kc < K; kc += 64){
    // stage 64x64 f16 chunk with xor swizzle (byte ^= seg^(row&7))
    #pragma unroll
    for (int c = tid; c < 512; c += 256){
      int row = c >> 3, seg = c & 7;
      f16x8 v = *(const f16x8*)(X + (size_t)(m0+row)*K + kc + seg*8);
      *(f16x8*)(Asb + row*128 + (((seg ^ (row&7)))<<4)) = v;
    }
    __syncthreads();
    #pragma unroll
    for (int kt2 = 0; kt2 < 2; ++kt2){
      int kt = (kc >> 5) + kt2;
      f16x8 bf = *(const f16x8*)(WB + ((size_t)(kt*512 + n0 + w*16 + (lane&15))*4 + (lane>>4))*8);
      #pragma unroll
      for (int mt = 0; mt < 4; ++mt){
        int r  = mt*16 + (lane & 15);
        int x8 = kt2*4 + (lane >> 4);
        f16x8 af = *(const f16x8*)(Asb + r*128 + (((x8 ^ (r&7)))<<4));
        acc[mt] = __builtin_amdgcn_mfma_f32_16x16x32_f16(af, bf, acc[mt], 0,0,0);
      }
    }
    __syncthreads();
  }
  #pragma unroll
  for (int mt = 0; mt < 4; ++mt)
    #pragma unroll
    for (int j = 0; j < 4; ++j){
      int m = m0 + mt*16 + (lane>>4)*4 + j;
      int n = n0 + w*16 + (lane&15);
      XW[(size_t)m*512 + n] = acc[mt][j];
    }
}

// ---------------- recurrence ----------------
// one WG per batch; thread n owns output n. h double-buffered in LDS (f16).
// MODE 0: write h row-major f16 [m][512]; MODE 1: write FC packed flatB layout.
template<int MODE>
__global__ __launch_bounds__(512,1) void k_rec(const float* __restrict__ XW,
        const _Float16* __restrict__ W8, const float* __restrict__ bias,
        _Float16* __restrict__ OUT){
  __shared__ __align__(16) _Float16 h2[2][512];
  const int b = blockIdx.x, n = threadIdx.x;
  const float bia = bias[n];
  h2[0][n] = (_Float16)0.0f;
  __syncthreads();
  int cur = 0;
  const f16x8* wp = ((const f16x8*)W8) + n;
  for (int t = 0; t < 256; ++t){
    float xv = XW[(size_t)((b<<8) + t)*512 + n];
    const f16x8* hp = (const f16x8*)(h2[cur]);
    float d0=0.f, d1=0.f, d2=0.f, d3=0.f;
    #pragma unroll 8
    for (int kc = 0; kc < 64; ++kc){
      f16x8 wv = wp[kc*512];
      f16x8 hv = hp[kc];
      f16x2 wa = __builtin_shufflevector(wv,wv,0,1), ha = __builtin_shufflevector(hv,hv,0,1);
      f16x2 wb2= __builtin_shufflevector(wv,wv,2,3), hb = __builtin_shufflevector(hv,hv,2,3);
      f16x2 wc = __builtin_shufflevector(wv,wv,4,5), hc = __builtin_shufflevector(hv,hv,4,5);
      f16x2 wd = __builtin_shufflevector(wv,wv,6,7), hd = __builtin_shufflevector(hv,hv,6,7);
      FDOT2(wa,ha,d0); FDOT2(wb2,hb,d1); FDOT2(wc,hc,d2); FDOT2(wd,hd,d3);
    }
    float y = tanh_fast(bia + xv + ((d0+d1)+(d2+d3)));
    if (MODE == 0) OUT[(size_t)((b<<8)+t)*512 + n] = (_Float16)y;
    else           OUT[(size_t)((t<<4) + (n>>5))*2048 + (b<<5) + (n&31)] = (_Float16)y;
    h2[cur^1][n] = (_Float16)y;
    __syncthreads();
    cur ^= 1;
  }
}

// ---------------- FC: out[m][n] = sum_k flat[m][k]*fcw[n][k] ----------------
// A = fc_w rows (fp32 stream + inline f16 cvt), B = flatB packed [kt][64][4][8].
// grid (4 ntiles of 256 rows, 64 ksplits of 2048), block 512 (8 waves).
__global__ __launch_bounds__(512,1) void k_fc(const float* __restrict__ W,
        const _Float16* __restrict__ FB, float* __restrict__ part){
  const int n0 = blockIdx.x*256;
  const int kb = blockIdx.y;
  const int k0 = kb*2048;
  const int tid = threadIdx.x, lane = tid & 63, w = tid >> 6;
  const int q = w >> 2, s = w & 3;
  f32x4 acc[8] = {{0,0,0,0},{0,0,0,0},{0,0,0,0},{0,0,0,0},
                  {0,0,0,0},{0,0,0,0},{0,0,0,0},{0,0,0,0}};
  for (int ks = 0; ks < 2048; ks += 32){
    int kt = (k0 + ks) >> 5;
    f16x8 bf = *(const f16x8*)(FB + ((size_t)(kt*64 + s*16 + (lane&15))*4 + (lane>>4))*8);
    #pragma unroll
    for (int mt = 0; mt < 8; ++mt){
      int row = n0 + (q*8 + mt)*16 + (lane & 15);
      if (row > 999) row = 999;
      const float* ap = W + (size_t)row*KFC + k0 + ks + (lane>>4)*8;
      float4 a0 = *(const float4*)ap;
      float4 a1 = *(const float4*)(ap + 4);
      f16x8 af = {(_Float16)a0.x,(_Float16)a0.y,(_Float16)a0.z,(_Float16)a0.w,
                  (_Float16)a1.x,(_Float16)a1.y,(_Float16)a1.z,(_Float16)a1.w};
      acc[mt] = __builtin_amdgcn_mfma_f32_16x16x32_f16(af, bf, acc[mt], 0,0,0);
    }
  }
  #pragma unroll
  for (int mt = 0; mt < 8; ++mt)
    #pragma unroll
    for (int j = 0; j < 4; ++j){
      int n = n0 + (q*8 + mt)*16 + (lane>>4)*4 + j;
      int m = s*16 + (lane & 15);
      if (n < 1000) part[(size_t)kb*64000 + m*1000 + n] = acc[mt][j];
    }
}

__global__ void k_reduce(const float* __restrict__ part, const float* __restrict__ fcb,
                         float* __restrict__ out){
  int i = blockIdx.x*256 + threadIdx.x;
  if (i >= 64000) return;
  float sacc = fcb[i % 1000];
  #pragma unroll 8
  for (int kb = 0; kb < 64; ++kb) sacc += part[(size_t)kb*64000 + i];
  out[i] = sacc;
}

// ---------------- launch ----------------
extern "C" void kernel_launch(void* const* d_in, const int* in_sizes, int n_in,
                              void* d_out, int out_size, void* d_ws, size_t ws_size,
                              hipStream_t stream) {
  const float* inp  = (const float*)d_in[0];
  const float* Wih0 = (const float*)d_in[1];
  const float* Whh0 = (const float*)d_in[2];
  const float* bih0 = (const float*)d_in[3];
  const float* bhh0 = (const float*)d_in[4];
  const float* Wih1 = (const float*)d_in[5];
  const float* Whh1 = (const float*)d_in[6];
  const float* bih1 = (const float*)d_in[7];
  const float* bhh1 = (const float*)d_in[8];
  const float* fcw  = (const float*)d_in[9];
  const float* fcb  = (const float*)d_in[10];
  float* out = (float*)d_out;
  char* ws = (char*)d_ws;

  _Float16* xf    = (_Float16*)(ws + 0);          //  8,388,608
  _Float16* WB0   = (_Float16*)(ws + 8388608);    //    262,144
  _Float16* WB1   = (_Float16*)(ws + 8650752);    //    524,288
  _Float16* W80   = (_Float16*)(ws + 9175040);    //    524,288
  _Float16* W81   = (_Float16*)(ws + 9699328);    //    524,288
  float*    bias0 = (float*)   (ws + 10223616);   //      2,048
  float*    bias1 = (float*)   (ws + 10225664);   //      2,048
  float*    xw    = (float*)   (ws + 10227712);   // 33,554,432 (reused both layers)
  _Float16* h0    = (_Float16*)(ws + 43782144);   // 16,777,216
  _Float16* flatB = (_Float16*)(ws + 60559360);   // 16,777,216
  float*    part  = (float*)   (ws + 77336576);   // 16,384,000  (end ~93.7MB)

  // prep
  k_cvt_x  <<<4096,256,0,stream>>>(inp, xf);
  k_pack_wb<<<  64,256,0,stream>>>(Wih0, WB0, 256);
  k_pack_wb<<< 128,256,0,stream>>>(Wih1, WB1, 512);
  k_pack_w8<<< 128,256,0,stream>>>(Whh0, W80);
  k_pack_w8<<< 128,256,0,stream>>>(Whh1, W81);
  k_bias   <<<   2,256,0,stream>>>(bih0, bhh0, bias0);
  k_bias   <<<   2,256,0,stream>>>(bih1, bhh1, bias1);

  // layer 0
  k_affine<256><<<dim3(256,8),256,0,stream>>>(xf, WB0, xw);
  k_rec<0>     <<<64,512,0,stream>>>(xw, W80, bias0, h0);
  // layer 1
  k_affine<512><<<dim3(256,8),256,0,stream>>>(h0, WB1, xw);
  k_rec<1>     <<<64,512,0,stream>>>(xw, W81, bias1, flatB);
  // FC
  k_fc   <<<dim3(4,64),512,0,stream>>>(fcw, flatB, part);
  k_reduce<<<250,256,0,stream>>>(part, fcb, out);
}

// Round 2
// 1272.502 us; speedup vs baseline: 1.9306x; 1.9306x over previous
//
#include <hip/hip_runtime.h>
#include <hip/hip_bf16.h>
#include <hip/hip_fp16.h>

#define B_ 64
#define T_ 256
#define D_ 256
#define H_ 512
#define C_ 1000
#define M_ (B_*T_)      // 16384
#define KFC (T_*H_)     // 131072

typedef _Float16 f16x2 __attribute__((ext_vector_type(2)));
typedef _Float16 f16x4 __attribute__((ext_vector_type(4)));
typedef _Float16 f16x8 __attribute__((ext_vector_type(8)));
typedef float    f32x4 __attribute__((ext_vector_type(4)));

#if defined(__has_builtin)
#if __has_builtin(__builtin_amdgcn_fdot2)
#define FDOT2(w,h,acc) (acc) = __builtin_amdgcn_fdot2((w),(h),(acc),false)
#endif
#endif
#ifndef FDOT2
#define FDOT2(w,h,acc) (acc) += (float)(w)[0]*(float)(h)[0] + (float)(w)[1]*(float)(h)[1]
#endif

#define DOT8(wv,hv,d0,d1,d2,d3) do{                                            \
  f16x2 wa = __builtin_shufflevector((wv),(wv),0,1), ha = __builtin_shufflevector((hv),(hv),0,1); \
  f16x2 wb = __builtin_shufflevector((wv),(wv),2,3), hb = __builtin_shufflevector((hv),(hv),2,3); \
  f16x2 wc = __builtin_shufflevector((wv),(wv),4,5), hc = __builtin_shufflevector((hv),(hv),4,5); \
  f16x2 wd = __builtin_shufflevector((wv),(wv),6,7), hd = __builtin_shufflevector((hv),(hv),6,7); \
  FDOT2(wa,ha,d0); FDOT2(wb,hb,d1); FDOT2(wc,hc,d2); FDOT2(wd,hd,d3);          \
}while(0)

__device__ __forceinline__ float tanh_fast(float x){
  float e = __expf(2.0f*x);
  return 1.0f - 2.0f/(e + 1.0f);
}

// ---------------- prep kernels ----------------

__global__ void k_cvt_x(const float* __restrict__ x, _Float16* __restrict__ o){
  int i = (blockIdx.x*256 + threadIdx.x)*4;
  float4 v = *(const float4*)(x + i);
  f16x4 r = {(_Float16)v.x,(_Float16)v.y,(_Float16)v.z,(_Float16)v.w};
  *(f16x4*)(o + i) = r;
}

// W [N=512][K] f32 row-major  ->  WB [K/32][512][4][8] f16 (MFMA B-frag layout)
__global__ void k_pack_wb(const float* __restrict__ W, _Float16* __restrict__ WB, int K){
  int id = blockIdx.x*256 + threadIdx.x;
  int g  = id & 3;
  int n  = (id >> 2) & 511;
  int kt = id >> 11;
  const float* src = W + (size_t)n*K + kt*32 + g*8;
  _Float16* dst = WB + ((size_t)(kt*512 + n)*4 + g)*8;
  #pragma unroll
  for (int j=0;j<8;++j) dst[j] = (_Float16)src[j];
}

// W_hh [512][512] f32 -> W8 [64][512][8] f16 (k-chunk-8 interleave)
__global__ void k_pack_w8(const float* __restrict__ W, _Float16* __restrict__ W8){
  int id = blockIdx.x*256 + threadIdx.x;
  int n  = id & 511;
  int kc = id >> 9;
  const float* src = W + (size_t)n*512 + kc*8;
  _Float16* dst = W8 + (size_t)(kc*512 + n)*8;
  #pragma unroll
  for (int j=0;j<8;++j) dst[j] = (_Float16)src[j];
}

__global__ void k_bias(const float* __restrict__ a, const float* __restrict__ b,
                       float* __restrict__ o){
  int i = blockIdx.x*256 + threadIdx.x;
  if (i < 512) o[i] = a[i] + b[i];
}

// ---------------- affine GEMM ----------------
template<int K>
__global__ __launch_bounds__(256,4) void k_affine(const _Float16* __restrict__ X,
        const _Float16* __restrict__ WB, float* __restrict__ XW){
  __shared__ __align__(16) char Asb[64*128];
  const int m0 = blockIdx.x*64, n0 = blockIdx.y*64;
  const int tid = threadIdx.x, lane = tid & 63, w = tid >> 6;
  f32x4 acc[4] = {{0,0,0,0},{0,0,0,0},{0,0,0,0},{0,0,0,0}};

  for (int kc = 0; kc < K; kc += 64){
    #pragma unroll
    for (int c = tid; c < 512; c += 256){
      int row = c >> 3, seg = c & 7;
      f16x8 v = *(const f16x8*)(X + (size_t)(m0+row)*K + kc + seg*8);
      *(f16x8*)(Asb + row*128 + (((seg ^ (row&7)))<<4)) = v;
    }
    __syncthreads();
    #pragma unroll
    for (int kt2 = 0; kt2 < 2; ++kt2){
      int kt = (kc >> 5) + kt2;
      f16x8 bf = *(const f16x8*)(WB + ((size_t)(kt*512 + n0 + w*16 + (lane&15))*4 + (lane>>4))*8);
      #pragma unroll
      for (int mt = 0; mt < 4; ++mt){
        int r  = mt*16 + (lane & 15);
        int x8 = kt2*4 + (lane >> 4);
        f16x8 af = *(const f16x8*)(Asb + r*128 + (((x8 ^ (r&7)))<<4));
        acc[mt] = __builtin_amdgcn_mfma_f32_16x16x32_f16(af, bf, acc[mt], 0,0,0);
      }
    }
    __syncthreads();
  }
  #pragma unroll
  for (int mt = 0; mt < 4; ++mt)
    #pragma unroll
    for (int j = 0; j < 4; ++j){
      int m = m0 + mt*16 + (lane>>4)*4 + j;
      int n = n0 + w*16 + (lane&15);
      XW[(size_t)m*512 + n] = acc[mt][j];
    }
}

// ---------------- recurrence: CU-resident weights ----------------
// One WG (512 threads) per batch. Thread n owns output n.
// W row n: k-chunks 0..KV2-1 in VGPRs (f16x8 each), chunks KV2..63 in LDS.
#define KV2 45
#define KL2 (64-KV2)   // 19 chunks -> 19*8KB = 152KB dynamic LDS

template<int MODE>
__global__ __launch_bounds__(512,1) void k_rec2(const float* __restrict__ XW,
        const _Float16* __restrict__ W8, const float* __restrict__ bias,
        _Float16* __restrict__ OUT){
  extern __shared__ __align__(16) char smem[];
  _Float16* WL = (_Float16*)smem;                         // [KL2][512][8]
  _Float16* h2 = (_Float16*)(smem + (size_t)KL2*512*16);  // [2][512]
  const int b = blockIdx.x, n = threadIdx.x;
  const float bia = bias[n];
  const f16x8* wp = ((const f16x8*)W8) + n;   // W8 [64][512][8]

  f16x8 wr[KV2];
  #pragma unroll
  for (int kc = 0; kc < KV2; ++kc) wr[kc] = wp[kc*512];
  f16x8* wl = ((f16x8*)WL) + n;
  #pragma unroll
  for (int j = 0; j < KL2; ++j) wl[j*512] = wp[(KV2+j)*512];
  h2[n] = (_Float16)0.0f;
  __syncthreads();

  const float* xp = XW + (size_t)(b<<8)*512 + n;
  float xv = xp[0];
  int cur = 0;
  for (int t = 0; t < 256; ++t){
    float xv_next = xp[(size_t)(t < 255 ? t+1 : t)*512];   // prefetch next step
    const f16x8* hp = (const f16x8*)(h2 + cur*512);
    float d0=0.f, d1=0.f, d2=0.f, d3=0.f;
    #pragma unroll
    for (int kc = 0; kc < KV2; ++kc){
      f16x8 hv = hp[kc];
      DOT8(wr[kc], hv, d0,d1,d2,d3);
    }
    #pragma unroll
    for (int j = 0; j < KL2; ++j){
      f16x8 hv = hp[KV2+j];
      f16x8 wv = wl[j*512];
      DOT8(wv, hv, d0,d1,d2,d3);
    }
    float y = tanh_fast(bia + xv + ((d0+d1)+(d2+d3)));
    if (MODE == 0) OUT[((size_t)(b<<8)+t)*512 + n] = (_Float16)y;
    else           OUT[(size_t)((t<<4) + (n>>5))*2048 + (b<<5) + (n&31)] = (_Float16)y;
    h2[(cur^1)*512 + n] = (_Float16)y;
    __syncthreads();
    cur ^= 1;
    xv = xv_next;
  }
}

// ---------------- FC ----------------
__global__ __launch_bounds__(512,1) void k_fc(const float* __restrict__ W,
        const _Float16* __restrict__ FB, float* __restrict__ part){
  const int n0 = blockIdx.x*256;
  const int kb = blockIdx.y;
  const int k0 = kb*2048;
  const int tid = threadIdx.x, lane = tid & 63, w = tid >> 6;
  const int q = w >> 2, s = w & 3;
  f32x4 acc[8] = {{0,0,0,0},{0,0,0,0},{0,0,0,0},{0,0,0,0},
                  {0,0,0,0},{0,0,0,0},{0,0,0,0},{0,0,0,0}};
  for (int ks = 0; ks < 2048; ks += 32){
    int kt = (k0 + ks) >> 5;
    f16x8 bf = *(const f16x8*)(FB + ((size_t)(kt*64 + s*16 + (lane&15))*4 + (lane>>4))*8);
    #pragma unroll
    for (int mt = 0; mt < 8; ++mt){
      int row = n0 + (q*8 + mt)*16 + (lane & 15);
      if (row > 999) row = 999;
      const float* ap = W + (size_t)row*KFC + k0 + ks + (lane>>4)*8;
      float4 a0 = *(const float4*)ap;
      float4 a1 = *(const float4*)(ap + 4);
      f16x8 af = {(_Float16)a0.x,(_Float16)a0.y,(_Float16)a0.z,(_Float16)a0.w,
                  (_Float16)a1.x,(_Float16)a1.y,(_Float16)a1.z,(_Float16)a1.w};
      acc[mt] = __builtin_amdgcn_mfma_f32_16x16x32_f16(af, bf, acc[mt], 0,0,0);
    }
  }
  #pragma unroll
  for (int mt = 0; mt < 8; ++mt)
    #pragma unroll
    for (int j = 0; j < 4; ++j){
      int n = n0 + (q*8 + mt)*16 + (lane>>4)*4 + j;
      int m = s*16 + (lane & 15);
      if (n < 1000) part[(size_t)kb*64000 + m*1000 + n] = acc[mt][j];
    }
}

__global__ void k_reduce(const float* __restrict__ part, const float* __restrict__ fcb,
                         float* __restrict__ out){
  int i = blockIdx.x*256 + threadIdx.x;
  if (i >= 64000) return;
  float sacc = fcb[i % 1000];
  #pragma unroll 8
  for (int kb = 0; kb < 64; ++kb) sacc += part[(size_t)kb*64000 + i];
  out[i] = sacc;
}

// ---------------- launch ----------------
extern "C" void kernel_launch(void* const* d_in, const int* in_sizes, int n_in,
                              void* d_out, int out_size, void* d_ws, size_t ws_size,
                              hipStream_t stream) {
  const float* inp  = (const float*)d_in[0];
  const float* Wih0 = (const float*)d_in[1];
  const float* Whh0 = (const float*)d_in[2];
  const float* bih0 = (const float*)d_in[3];
  const float* bhh0 = (const float*)d_in[4];
  const float* Wih1 = (const float*)d_in[5];
  const float* Whh1 = (const float*)d_in[6];
  const float* bih1 = (const float*)d_in[7];
  const float* bhh1 = (const float*)d_in[8];
  const float* fcw  = (const float*)d_in[9];
  const float* fcb  = (const float*)d_in[10];
  float* out = (float*)d_out;
  char* ws = (char*)d_ws;

  _Float16* xf    = (_Float16*)(ws + 0);          //  8,388,608
  _Float16* WB0   = (_Float16*)(ws + 8388608);    //    262,144
  _Float16* WB1   = (_Float16*)(ws + 8650752);    //    524,288
  _Float16* W80   = (_Float16*)(ws + 9175040);    //    524,288
  _Float16* W81   = (_Float16*)(ws + 9699328);    //    524,288
  float*    bias0 = (float*)   (ws + 10223616);   //      2,048
  float*    bias1 = (float*)   (ws + 10225664);   //      2,048
  float*    xw    = (float*)   (ws + 10227712);   // 33,554,432 (reused both layers)
  _Float16* h0    = (_Float16*)(ws + 43782144);   // 16,777,216
  _Float16* flatB = (_Float16*)(ws + 60559360);   // 16,777,216
  float*    part  = (float*)   (ws + 77336576);   // 16,384,000

  const size_t lds_rec = (size_t)KL2*512*16 + 2*512*2;   // 155,648 + 2,048 = 157,696 B
  (void)hipFuncSetAttribute(reinterpret_cast<const void*>(k_rec2<0>),
                            hipFuncAttributeMaxDynamicSharedMemorySize, (int)lds_rec);
  (void)hipFuncSetAttribute(reinterpret_cast<const void*>(k_rec2<1>),
                            hipFuncAttributeMaxDynamicSharedMemorySize, (int)lds_rec);

  // prep
  k_cvt_x  <<<4096,256,0,stream>>>(inp, xf);
  k_pack_wb<<<  64,256,0,stream>>>(Wih0, WB0, 256);
  k_pack_wb<<< 128,256,0,stream>>>(Wih1, WB1, 512);
  k_pack_w8<<< 128,256,0,stream>>>(Whh0, W80);
  k_pack_w8<<< 128,256,0,stream>>>(Whh1, W81);
  k_bias   <<<   2,256,0,stream>>>(bih0, bhh0, bias0);
  k_bias   <<<   2,256,0,stream>>>(bih1, bhh1, bias1);

  // layer 0
  k_affine<256><<<dim3(256,8),256,0,stream>>>(xf, WB0, xw);
  k_rec2<0>    <<<64,512,lds_rec,stream>>>(xw, W80, bias0, h0);
  // layer 1
  k_affine<512><<<dim3(256,8),256,0,stream>>>(h0, WB1, xw);
  k_rec2<1>    <<<64,512,lds_rec,stream>>>(xw, W81, bias1, flatB);
  // FC
  k_fc   <<<dim3(4,64),512,0,stream>>>(fcw, flatB, part);
  k_reduce<<<250,256,0,stream>>>(part, fcb, out);
}

// Round 3
// 1121.669 us; speedup vs baseline: 2.1902x; 1.1345x over previous
//
#include <hip/hip_runtime.h>
#include <hip/hip_bf16.h>
#include <hip/hip_fp16.h>

#define B_ 64
#define T_ 256
#define D_ 256
#define H_ 512
#define C_ 1000
#define M_ (B_*T_)      // 16384
#define KFC (T_*H_)     // 131072

typedef _Float16 f16x2 __attribute__((ext_vector_type(2)));
typedef _Float16 f16x4 __attribute__((ext_vector_type(4)));
typedef _Float16 f16x8 __attribute__((ext_vector_type(8)));
typedef float    f32x4 __attribute__((ext_vector_type(4)));

#if defined(__has_builtin)
#if __has_builtin(__builtin_amdgcn_fdot2)
#define FDOT2(w,h,acc) (acc) = __builtin_amdgcn_fdot2((w),(h),(acc),false)
#endif
#endif
#ifndef FDOT2
#define FDOT2(w,h,acc) (acc) += (float)(w)[0]*(float)(h)[0] + (float)(w)[1]*(float)(h)[1]
#endif

#define DOT8(wv,hv,d0,d1,d2,d3) do{                                            \
  f16x2 wa = __builtin_shufflevector((wv),(wv),0,1), ha = __builtin_shufflevector((hv),(hv),0,1); \
  f16x2 wb = __builtin_shufflevector((wv),(wv),2,3), hb = __builtin_shufflevector((hv),(hv),2,3); \
  f16x2 wc = __builtin_shufflevector((wv),(wv),4,5), hc = __builtin_shufflevector((hv),(hv),4,5); \
  f16x2 wd = __builtin_shufflevector((wv),(wv),6,7), hd = __builtin_shufflevector((hv),(hv),6,7); \
  FDOT2(wa,ha,d0); FDOT2(wb,hb,d1); FDOT2(wc,hc,d2); FDOT2(wd,hd,d3);          \
}while(0)

__device__ __forceinline__ float tanh_fast(float x){
  float e = __expf(2.0f*x);
  return 1.0f - 2.0f/(e + 1.0f);
}

// ---------------- prep kernels ----------------

__global__ void k_cvt_x(const float* __restrict__ x, _Float16* __restrict__ o){
  int i = (blockIdx.x*256 + threadIdx.x)*4;
  float4 v = *(const float4*)(x + i);
  f16x4 r = {(_Float16)v.x,(_Float16)v.y,(_Float16)v.z,(_Float16)v.w};
  *(f16x4*)(o + i) = r;
}

// W [N=512][K] f32 row-major  ->  WB [K/32][512][4][8] f16 (MFMA B-frag layout)
__global__ void k_pack_wb(const float* __restrict__ W, _Float16* __restrict__ WB, int K){
  int id = blockIdx.x*256 + threadIdx.x;
  int g  = id & 3;
  int n  = (id >> 2) & 511;
  int kt = id >> 11;
  const float* src = W + (size_t)n*K + kt*32 + g*8;
  _Float16* dst = WB + ((size_t)(kt*512 + n)*4 + g)*8;
  #pragma unroll
  for (int j=0;j<8;++j) dst[j] = (_Float16)src[j];
}

// W_hh [512][512] f32 -> W8 [64][512][8] f16 (k-chunk-8 interleave)
__global__ void k_pack_w8(const float* __restrict__ W, _Float16* __restrict__ W8){
  int id = blockIdx.x*256 + threadIdx.x;
  int n  = id & 511;
  int kc = id >> 9;
  const float* src = W + (size_t)n*512 + kc*8;
  _Float16* dst = W8 + (size_t)(kc*512 + n)*8;
  #pragma unroll
  for (int j=0;j<8;++j) dst[j] = (_Float16)src[j];
}

__global__ void k_bias(const float* __restrict__ a, const float* __restrict__ b,
                       float* __restrict__ o){
  int i = blockIdx.x*256 + threadIdx.x;
  if (i < 512) o[i] = a[i] + b[i];
}

// ---------------- affine GEMM ----------------
template<int K>
__global__ __launch_bounds__(256,4) void k_affine(const _Float16* __restrict__ X,
        const _Float16* __restrict__ WB, float* __restrict__ XW){
  __shared__ __align__(16) char Asb[64*128];
  const int m0 = blockIdx.x*64, n0 = blockIdx.y*64;
  const int tid = threadIdx.x, lane = tid & 63, w = tid >> 6;
  f32x4 acc[4] = {{0,0,0,0},{0,0,0,0},{0,0,0,0},{0,0,0,0}};

  for (int kc = 0; kc < K; kc += 64){
    #pragma unroll
    for (int c = tid; c < 512; c += 256){
      int row = c >> 3, seg = c & 7;
      f16x8 v = *(const f16x8*)(X + (size_t)(m0+row)*K + kc + seg*8);
      *(f16x8*)(Asb + row*128 + (((seg ^ (row&7)))<<4)) = v;
    }
    __syncthreads();
    #pragma unroll
    for (int kt2 = 0; kt2 < 2; ++kt2){
      int kt = (kc >> 5) + kt2;
      f16x8 bf = *(const f16x8*)(WB + ((size_t)(kt*512 + n0 + w*16 + (lane&15))*4 + (lane>>4))*8);
      #pragma unroll
      for (int mt = 0; mt < 4; ++mt){
        int r  = mt*16 + (lane & 15);
        int x8 = kt2*4 + (lane >> 4);
        f16x8 af = *(const f16x8*)(Asb + r*128 + (((x8 ^ (r&7)))<<4));
        acc[mt] = __builtin_amdgcn_mfma_f32_16x16x32_f16(af, bf, acc[mt], 0,0,0);
      }
    }
    __syncthreads();
  }
  #pragma unroll
  for (int mt = 0; mt < 4; ++mt)
    #pragma unroll
    for (int j = 0; j < 4; ++j){
      int m = m0 + mt*16 + (lane>>4)*4 + j;
      int n = n0 + w*16 + (lane&15);
      XW[(size_t)m*512 + n] = acc[mt][j];
    }
}

// ---------------- recurrence: CU-resident weights ----------------
#define KV2 45
#define KL2 (64-KV2)   // 19 chunks -> 152KB dynamic LDS

template<int MODE>
__global__ __launch_bounds__(512,1) void k_rec2(const float* __restrict__ XW,
        const _Float16* __restrict__ W8, const float* __restrict__ bias,
        _Float16* __restrict__ OUT){
  extern __shared__ __align__(16) char smem[];
  _Float16* WL = (_Float16*)smem;                         // [KL2][512][8]
  _Float16* h2 = (_Float16*)(smem + (size_t)KL2*512*16);  // [2][512]
  const int b = blockIdx.x, n = threadIdx.x;
  const float bia = bias[n];
  const f16x8* wp = ((const f16x8*)W8) + n;   // W8 [64][512][8]

  f16x8 wr[KV2];
  #pragma unroll
  for (int kc = 0; kc < KV2; ++kc) wr[kc] = wp[kc*512];
  f16x8* wl = ((f16x8*)WL) + n;
  #pragma unroll
  for (int j = 0; j < KL2; ++j) wl[j*512] = wp[(KV2+j)*512];
  h2[n] = (_Float16)0.0f;
  __syncthreads();

  const float* xp = XW + (size_t)(b<<8)*512 + n;
  float xv = xp[0];
  int cur = 0;
  for (int t = 0; t < 256; ++t){
    float xv_next = xp[(size_t)(t < 255 ? t+1 : t)*512];   // prefetch next step
    const f16x8* hp = (const f16x8*)(h2 + cur*512);
    float d0=0.f, d1=0.f, d2=0.f, d3=0.f;
    #pragma unroll
    for (int kc = 0; kc < KV2; ++kc){
      f16x8 hv = hp[kc];
      DOT8(wr[kc], hv, d0,d1,d2,d3);
    }
    #pragma unroll
    for (int j = 0; j < KL2; ++j){
      f16x8 hv = hp[KV2+j];
      f16x8 wv = wl[j*512];
      DOT8(wv, hv, d0,d1,d2,d3);
    }
    float y = tanh_fast(bia + xv + ((d0+d1)+(d2+d3)));
    if (MODE == 0) OUT[((size_t)(b<<8)+t)*512 + n] = (_Float16)y;
    else           OUT[(size_t)((t<<4) + (n>>5))*2048 + (b<<5) + (n&31)] = (_Float16)y;
    h2[(cur^1)*512 + n] = (_Float16)y;
    __syncthreads();
    cur ^= 1;
    xv = xv_next;
  }
}

// ---------------- FC: out[m][n] = sum_k flat[m][k]*fcw[n][k] ----------------
// grid (16 n-tiles of 64 rows, 64 k-splits of 2048), block 512 -> 1024 WGs,
// 4 WGs/CU = 32 waves/CU (full occupancy). Each wave: 2 row-tiles x 1 m-tile.
__global__ __launch_bounds__(512,1) void k_fc(const float* __restrict__ W,
        const _Float16* __restrict__ FB, float* __restrict__ part){
  const int n0 = blockIdx.x*64;
  const int kb = blockIdx.y;
  const int k0 = kb*2048;
  const int tid = threadIdx.x, lane = tid & 63, w = tid >> 6;
  const int q = w >> 2, s = w & 3;     // q: row-half, s: m-tile
  f32x4 acc[2] = {{0,0,0,0},{0,0,0,0}};
  for (int ks = 0; ks < 2048; ks += 32){
    int kt = (k0 + ks) >> 5;
    f16x8 bf = *(const f16x8*)(FB + ((size_t)(kt*64 + s*16 + (lane&15))*4 + (lane>>4))*8);
    #pragma unroll
    for (int mt = 0; mt < 2; ++mt){
      int row = n0 + (q*2 + mt)*16 + (lane & 15);
      if (row > 999) row = 999;
      const float* ap = W + (size_t)row*KFC + k0 + ks + (lane>>4)*8;
      float4 a0 = *(const float4*)ap;
      float4 a1 = *(const float4*)(ap + 4);
      f16x8 af = {(_Float16)a0.x,(_Float16)a0.y,(_Float16)a0.z,(_Float16)a0.w,
                  (_Float16)a1.x,(_Float16)a1.y,(_Float16)a1.z,(_Float16)a1.w};
      acc[mt] = __builtin_amdgcn_mfma_f32_16x16x32_f16(af, bf, acc[mt], 0,0,0);
    }
  }
  #pragma unroll
  for (int mt = 0; mt < 2; ++mt)
    #pragma unroll
    for (int j = 0; j < 4; ++j){
      int n = n0 + (q*2 + mt)*16 + (lane>>4)*4 + j;
      int m = s*16 + (lane & 15);
      if (n < 1000) part[(size_t)kb*64000 + m*1000 + n] = acc[mt][j];
    }
}

__global__ void k_reduce(const float* __restrict__ part, const float* __restrict__ fcb,
                         float* __restrict__ out){
  int i = blockIdx.x*256 + threadIdx.x;
  if (i >= 64000) return;
  float sacc = fcb[i % 1000];
  #pragma unroll 8
  for (int kb = 0; kb < 64; ++kb) sacc += part[(size_t)kb*64000 + i];
  out[i] = sacc;
}

// ---------------- launch ----------------
extern "C" void kernel_launch(void* const* d_in, const int* in_sizes, int n_in,
                              void* d_out, int out_size, void* d_ws, size_t ws_size,
                              hipStream_t stream) {
  const float* inp  = (const float*)d_in[0];
  const float* Wih0 = (const float*)d_in[1];
  const float* Whh0 = (const float*)d_in[2];
  const float* bih0 = (const float*)d_in[3];
  const float* bhh0 = (const float*)d_in[4];
  const float* Wih1 = (const float*)d_in[5];
  const float* Whh1 = (const float*)d_in[6];
  const float* bih1 = (const float*)d_in[7];
  const float* bhh1 = (const float*)d_in[8];
  const float* fcw  = (const float*)d_in[9];
  const float* fcb  = (const float*)d_in[10];
  float* out = (float*)d_out;
  char* ws = (char*)d_ws;

  _Float16* xf    = (_Float16*)(ws + 0);          //  8,388,608
  _Float16* WB0   = (_Float16*)(ws + 8388608);    //    262,144
  _Float16* WB1   = (_Float16*)(ws + 8650752);    //    524,288
  _Float16* W80   = (_Float16*)(ws + 9175040);    //    524,288
  _Float16* W81   = (_Float16*)(ws + 9699328);    //    524,288
  float*    bias0 = (float*)   (ws + 10223616);   //      2,048
  float*    bias1 = (float*)   (ws + 10225664);   //      2,048
  float*    xw    = (float*)   (ws + 10227712);   // 33,554,432 (reused both layers)
  _Float16* h0    = (_Float16*)(ws + 43782144);   // 16,777,216
  _Float16* flatB = (_Float16*)(ws + 60559360);   // 16,777,216
  float*    part  = (float*)   (ws + 77336576);   // 16,384,000

  const size_t lds_rec = (size_t)KL2*512*16 + 2*512*2;   // 157,696 B
  (void)hipFuncSetAttribute(reinterpret_cast<const void*>(k_rec2<0>),
                            hipFuncAttributeMaxDynamicSharedMemorySize, (int)lds_rec);
  (void)hipFuncSetAttribute(reinterpret_cast<const void*>(k_rec2<1>),
                            hipFuncAttributeMaxDynamicSharedMemorySize, (int)lds_rec);

  // prep
  k_cvt_x  <<<4096,256,0,stream>>>(inp, xf);
  k_pack_wb<<<  64,256,0,stream>>>(Wih0, WB0, 256);
  k_pack_wb<<< 128,256,0,stream>>>(Wih1, WB1, 512);
  k_pack_w8<<< 128,256,0,stream>>>(Whh0, W80);
  k_pack_w8<<< 128,256,0,stream>>>(Whh1, W81);
  k_bias   <<<   2,256,0,stream>>>(bih0, bhh0, bias0);
  k_bias   <<<   2,256,0,stream>>>(bih1, bhh1, bias1);

  // layer 0
  k_affine<256><<<dim3(256,8),256,0,stream>>>(xf, WB0, xw);
  k_rec2<0>    <<<64,512,lds_rec,stream>>>(xw, W80, bias0, h0);
  // layer 1
  k_affine<512><<<dim3(256,8),256,0,stream>>>(h0, WB1, xw);
  k_rec2<1>    <<<64,512,lds_rec,stream>>>(xw, W81, bias1, flatB);
  // FC
  k_fc   <<<dim3(16,64),512,0,stream>>>(fcw, flatB, part);
  k_reduce<<<250,256,0,stream>>>(part, fcb, out);
}